// Round 20
// baseline (376.500 us; speedup 1.0000x reference)
//
#include <hip/hip_runtime.h>

typedef unsigned short u16;
typedef __bf16 bf16x8_t __attribute__((ext_vector_type(8)));
typedef float f32x4 __attribute__((ext_vector_type(4)));
typedef u16 u16x8 __attribute__((ext_vector_type(8)));
typedef u16 u16x4 __attribute__((ext_vector_type(4)));

__device__ __forceinline__ u16 f2bf(float f) {
  union { float f; unsigned u; } v; v.f = f;
  unsigned r = v.u + 0x7FFFu + ((v.u >> 16) & 1u);
  return (u16)(r >> 16);
}
__device__ __forceinline__ float bf2f(u16 b) {
  union { unsigned u; float f; } v; v.u = ((unsigned)b) << 16;
  return v.f;
}
__device__ __forceinline__ f32x4 mfma_bf16(u16x8 a, u16x8 b, f32x4 c) {
  return __builtin_amdgcn_mfma_f32_16x16x32_bf16(
      __builtin_bit_cast(bf16x8_t, a), __builtin_bit_cast(bf16x8_t, b), c, 0, 0, 0);
}
// two f32 -> two TRUNCATED bf16 in one v_perm_b32 (bytes: a.hi16 -> low, b.hi16 -> high)
__device__ __forceinline__ unsigned pack_bf16_trunc(float a, float b) {
  return __builtin_amdgcn_perm(__builtin_bit_cast(unsigned, b),
                               __builtin_bit_cast(unsigned, a), 0x07060302u);
}

// ---------------- fused f32 -> bf16 convert (x, wq, wk, wv, wo in one launch) --------
__global__ void k_cvt_all(const float* __restrict__ x,  const float* __restrict__ wq,
                          const float* __restrict__ wk, const float* __restrict__ wv,
                          const float* __restrict__ wo, u16* __restrict__ xb,
                          u16* __restrict__ wqkvb, u16* __restrict__ wob) {
  const int i = blockIdx.x * blockDim.x + threadIdx.x;   // float4 index, < 4718592
  const float* src;
  u16* dst;
  int off;
  if (i < 2097152)      { src = x;  dst = xb;               off = i; }
  else if (i < 3145728) { src = wq; dst = wqkvb;            off = i - 2097152; }
  else if (i < 3407872) { src = wk; dst = wqkvb + 4194304;  off = i - 3145728; }
  else if (i < 3670016) { src = wv; dst = wqkvb + 5242880;  off = i - 3407872; }
  else                  { src = wo; dst = wob;              off = i - 3670016; }
  float4 v = reinterpret_cast<const float4*>(src)[off];
  u16x4 o = { f2bf(v.x), f2bf(v.y), f2bf(v.z), f2bf(v.w) };
  reinterpret_cast<u16x4*>(dst)[off] = o;
}

// ---------------- GEMM: C[M][N] = A[M][K] * B[N][K]^T (both bf16 row-major, K-major) ----
template<bool BF16OUT>
__global__ __launch_bounds__(256, 2)
void k_gemm_bt(const u16* __restrict__ A, const u16* __restrict__ B,
               void* __restrict__ Cv, int M, int N, int K) {
  __shared__ u16 lA[128 * 64];
  __shared__ u16 lB[128 * 64];
  const int bm = blockIdx.y, bn = blockIdx.x;
  const int tid = threadIdx.x;
  const int wid = tid >> 6, lane = tid & 63;
  const int lo = lane & 15, hi = lane >> 4;
  const int wrow = (wid >> 1) * 64, wcol = (wid & 1) * 64;
  f32x4 acc[4][4] = {};
  const size_t abase = (size_t)(bm * 128) * K;
  const size_t bbase = (size_t)(bn * 128) * K;
  for (int kt = 0; kt < K; kt += 64) {
#pragma unroll
    for (int rr = 0; rr < 4; ++rr) {
      int e = (rr * 256 + tid) * 8;
      int row = e >> 6, col = e & 63;
      u16x8 va = *reinterpret_cast<const u16x8*>(A + abase + (size_t)row * K + kt + col);
      u16x8 vb = *reinterpret_cast<const u16x8*>(B + bbase + (size_t)row * K + kt + col);
      int sw = ((row * 64 + col) * 2) ^ ((row & 7) << 4);
      *reinterpret_cast<u16x8*>(reinterpret_cast<char*>(lA) + sw) = va;
      *reinterpret_cast<u16x8*>(reinterpret_cast<char*>(lB) + sw) = vb;
    }
    __syncthreads();
#pragma unroll
    for (int ks = 0; ks < 64; ks += 32) {
      u16x8 af[4], bfr[4];
#pragma unroll
      for (int mi = 0; mi < 4; ++mi) {
        int row = wrow + mi * 16 + lo, col = ks + hi * 8;
        int sw = ((row * 64 + col) * 2) ^ ((row & 7) << 4);
        af[mi] = *reinterpret_cast<const u16x8*>(reinterpret_cast<char*>(lA) + sw);
      }
#pragma unroll
      for (int ni = 0; ni < 4; ++ni) {
        int row = wcol + ni * 16 + lo, col = ks + hi * 8;
        int sw = ((row * 64 + col) * 2) ^ ((row & 7) << 4);
        bfr[ni] = *reinterpret_cast<const u16x8*>(reinterpret_cast<char*>(lB) + sw);
      }
#pragma unroll
      for (int mi = 0; mi < 4; ++mi)
#pragma unroll
        for (int ni = 0; ni < 4; ++ni)
          acc[mi][ni] = mfma_bf16(af[mi], bfr[ni], acc[mi][ni]);
    }
    __syncthreads();
  }
#pragma unroll
  for (int mi = 0; mi < 4; ++mi)
#pragma unroll
    for (int ni = 0; ni < 4; ++ni)
#pragma unroll
      for (int r = 0; r < 4; ++r) {
        int row = bm * 128 + wrow + mi * 16 + hi * 4 + r;
        int col = bn * 128 + wcol + ni * 16 + lo;
        if (BF16OUT)
          ((u16*)Cv)[(size_t)row * N + col] = f2bf(acc[mi][ni][r]);
        else
          ((float*)Cv)[(size_t)row * N + col] = acc[mi][ni][r];
      }
}

// ---------------- FUSED RoPE + QK RMSNorm + V transpose (one dispatch) ----------------
// blocks [0, 20480): rope+norm on (t, head) pairs; Q pre-scaled by scale*log2e.
// blocks [20480, 20992): V transpose -> V^T [4][128][4096] in MFMA slot order.
#define ATT_SL2E 0.12754276432973518f   /* (1/sqrt(128)) * log2(e) */
__global__ void k_rope_tv(const u16* __restrict__ QKV, const float* __restrict__ qkw,
                          u16* __restrict__ qb, u16* __restrict__ kb,
                          u16* __restrict__ vtb) {
  __shared__ float lt[64][65];
  const int tid = threadIdx.x;
  if (blockIdx.x < 20480) {
    int gw = blockIdx.x * 4 + (tid >> 6);
    int lane = tid & 63;
    int t = gw / 20, hh = gw - t * 20;
    const u16* src = QKV + (size_t)t * 3072 + (hh < 16 ? hh * 128 : 2048 + (hh - 16) * 128);
    float x1 = bf2f(src[lane]), x2 = bf2f(src[lane + 64]);
    float invf = exp2f(-(float)lane * (13.287712379549449f / 64.0f)); // 10000^(-lane/64)
    float fr = (float)t * invf;
    float sn, cs;
    sincosf(fr, &sn, &cs);
    float o1 = x1 * cs - x2 * sn, o2 = x1 * sn + x2 * cs;
    float ss = o1 * o1 + o2 * o2;
#pragma unroll
    for (int off = 32; off > 0; off >>= 1) ss += __shfl_xor(ss, off);
    float inv = rsqrtf(ss * (1.0f / 128.0f) + 1e-6f);
    inv *= (hh < 16) ? ATT_SL2E : 1.0f;   // fold attention scale+log2e into Q
    o1 *= inv * qkw[lane];
    o2 *= inv * qkw[lane + 64];
    u16* dst = (hh < 16) ? (qb + ((size_t)hh * 4096 + t) * 128)
                         : (kb + ((size_t)(hh - 16) * 4096 + t) * 128);
    dst[lane] = f2bf(o1);
    dst[lane + 64] = f2bf(o2);
  } else {
    int b = blockIdx.x - 20480;
    int dt = b & 1, tt = (b >> 1) & 63, kv = b >> 7;
#pragma unroll
    for (int rr = 0; rr < 16; ++rr) {
      int row = rr * 4 + (tid >> 6);
      int col = tid & 63;
      lt[row][col] = bf2f(QKV[(size_t)(tt * 64 + row) * 3072 + 2560 + kv * 128 + dt * 64 + col]);
    }
    __syncthreads();
#pragma unroll
    for (int pp = 0; pp < 2; ++pp) {
      int idx = pp * 256 + tid;
      int dr = idx >> 3, tc = (idx & 7) * 8;
      const int grp = tc >> 5;           // 32-key group within the 64-key tile
      const int pb = tc & 31;            // position base within group (8-aligned)
      u16x8 o;
#pragma unroll
      for (int i = 0; i < 8; ++i) {
        const int p = pb + i;
        const int g = (p & 3) | (((p >> 3) & 3) << 2) | (((p >> 2) & 1) << 4);
        o[i] = f2bf(lt[grp * 32 + g][dr]);
      }
      *reinterpret_cast<u16x8*>(vtb + (size_t)(kv * 128 + dt * 64 + dr) * 4096 + tt * 64 + tc) = o;
    }
  }
}

// ---------------- MFMA flash attention, 2-deep pipeline (T15: QK[i] || finish[i-1]) --
// attend: j in [4, q-1023) union [q+1, 4096); K+V LDS-staged; XCD-kvh swizzle; setprio.
// lsum kept as f32x4 per-r accumulators (4 independent chains), reduced at the end.
#define KPAD 136   /* 32 x 136 u16: 272B = 17*16B */
#define VPAD 40    /* 128 x 40 u16: 80B = 5*16B  */

__global__ __launch_bounds__(256)
void k_attn_mfma(const u16* __restrict__ qb, const u16* __restrict__ kb,
                 const u16* __restrict__ vtb, u16* __restrict__ yb) {
  __shared__ u16 sK[2][32][KPAD];
  __shared__ u16 sV[2][128][VPAD];   // slot-order keys
  // XCD-kvh swizzle (bijective on [0,512)): xcd = id&7 owns work [xcd*64, xcd*64+64)
  const int id = blockIdx.x;
  const int work = (id & 7) * 64 + (id >> 3);
  const int kvh = work >> 7;               // 2 XCDs per kvh
  const int rem = work & 127;
  const int h = kvh * 4 + (rem >> 5);
  const int qt = rem & 31;
  const int tid = threadIdx.x;
  const int wid = tid >> 6, lane = tid & 63;
  const int lo = lane & 15, hi = lane >> 4;
  const int q0 = qt * 128;
  const int qwA = q0 + wid * 16;          // fragment A queries
  const int qwB = qwA + 64;               // fragment B queries
  const int qrowA = qwA + lo, qrowB = qwB + lo;
  const u16* qpA = qb + ((size_t)h * 4096 + qrowA) * 128;
  const u16* qpB = qb + ((size_t)h * 4096 + qrowB) * 128;
  u16x8 qfA[4], qfB[4];
#pragma unroll
  for (int dc = 0; dc < 4; ++dc) {
    qfA[dc] = *reinterpret_cast<const u16x8*>(qpA + dc * 32 + hi * 8);
    qfB[dc] = *reinterpret_cast<const u16x8*>(qpB + dc * 32 + hi * 8);
  }
  f32x4 accOA[8] = {}, accOB[8] = {};
  f32x4 ls4A = {}, ls4B = {};             // per-r partial lsums (4 short chains)
  const u16* kbase = kb + (size_t)kvh * 4096 * 128;
  const u16* vb = vtb + (size_t)kvh * 128 * 4096;

  // block-uniform tile list over 128 queries
  int past_tiles = 0;
  const int pe = q0 + 127 - 1024;
  if (pe >= 4) past_tiles = (pe >> 5) + 1;
  const int fstart = (q0 + 1) >> 5;
  const int ntiles = past_tiles + (128 - fstart);
  // mask-free (uniform over all 128 queries): past kt in [1, (q0-1055)>>5]; future kt >= (q0>>5)+4
  const int safe_past_hi = (q0 >= 1056) ? ((q0 - 1055) >> 5) : 0;
  const int funmask = (q0 >> 5) + 4;

#define KT_OF(i) (((i) < past_tiles) ? (i) : (fstart + ((i) - past_tiles)))
#define MSK_OF(i, ktv) (((i) < past_tiles) ? (((ktv) == 0) || ((ktv) > safe_past_hi)) \
                                           : ((ktv) < funmask))

  // pipeline registers: S and V of the previous (unfinished) tile
  f32x4 sSA[2], sSB[2];
  u16x8 vfp[8];
  int ktP = 0, mskP = 0;

  u16x8 kr[2], vr[2];
#define STAGE_LOAD(KT)                                                          \
  {                                                                             \
    const int kt_ = (KT);                                                       \
    _Pragma("unroll")                                                           \
    for (int p = 0; p < 2; ++p) {                                               \
      const int c = tid + p * 256;                                              \
      kr[p] = *reinterpret_cast<const u16x8*>(                                  \
          kbase + (size_t)(kt_ * 32 + (c >> 4)) * 128 + (c & 15) * 8);          \
      vr[p] = *reinterpret_cast<const u16x8*>(                                  \
          vb + (size_t)(c >> 2) * 4096 + kt_ * 32 + (c & 3) * 8);               \
    }                                                                           \
  }
#define STAGE_WRITE(BUF)                                                        \
  {                                                                             \
    const int b_ = (BUF);                                                       \
    _Pragma("unroll")                                                           \
    for (int p = 0; p < 2; ++p) {                                               \
      const int c = tid + p * 256;                                              \
      *reinterpret_cast<u16x8*>(&sK[b_][c >> 4][(c & 15) * 8]) = kr[p];         \
      *reinterpret_cast<u16x8*>(&sV[b_][c >> 2][(c & 3) * 8]) = vr[p];          \
    }                                                                           \
  }
#define QK_PHASE(CUR)                                                           \
    __builtin_amdgcn_s_setprio(1);                                              \
    _Pragma("unroll")                                                           \
    for (int sub = 0; sub < 2; ++sub)                                           \
      _Pragma("unroll")                                                         \
      for (int dc = 0; dc < 4; ++dc) {                                          \
        u16x8 kf = *reinterpret_cast<const u16x8*>(                             \
            &sK[CUR][sub * 16 + lo][dc * 32 + hi * 8]);                         \
        nSA[sub] = mfma_bf16(kf, qfA[dc], nSA[sub]);                            \
        nSB[sub] = mfma_bf16(kf, qfB[dc], nSB[sub]);                            \
      }                                                                         \
    __builtin_amdgcn_s_setprio(0);
#define VF_LOAD(CUR)                                                            \
    _Pragma("unroll")                                                           \
    for (int nt = 0; nt < 8; ++nt)                                              \
      vfp[nt] = *reinterpret_cast<const u16x8*>(&sV[CUR][nt * 16 + lo][hi * 8]);
  // softmax of the DEFERRED tile (registers sS*, ktP); MSKLIT folds at compile time
#define SOFT(MSKLIT)                                                            \
    _Pragma("unroll")                                                           \
    for (int sub = 0; sub < 2; ++sub) {                                         \
      float eA[4], eB[4];                                                       \
      _Pragma("unroll")                                                         \
      for (int r = 0; r < 4; ++r) {                                             \
        float pA = exp2f(sSA[sub][r]);                                          \
        float pB = exp2f(sSB[sub][r]);                                          \
        if (MSKLIT) {                                                           \
          const int j = ktP * 32 + sub * 16 + hi * 4 + r;                       \
          const bool okA = (j > qrowA) || (((qrowA - j) >= 1024) && (j >= 4));  \
          const bool okB = (j > qrowB) || (((qrowB - j) >= 1024) && (j >= 4));  \
          pA = okA ? pA : 0.0f;                                                 \
          pB = okB ? pB : 0.0f;                                                 \
        }                                                                       \
        ls4A[r] += pA; ls4B[r] += pB;                                           \
        eA[r] = pA; eB[r] = pB;                                                 \
      }                                                                         \
      wA[sub * 2]     = pack_bf16_trunc(eA[0], eA[1]);                          \
      wA[sub * 2 + 1] = pack_bf16_trunc(eA[2], eA[3]);                          \
      wB[sub * 2]     = pack_bf16_trunc(eB[0], eB[1]);                          \
      wB[sub * 2 + 1] = pack_bf16_trunc(eB[2], eB[3]);                          \
    }
#define FINISH()                                                                \
  {                                                                             \
    unsigned wA[4], wB[4];                                                      \
    if (mskP) { SOFT(true) } else { SOFT(false) }                               \
    uint4 tA4 = { wA[0], wA[1], wA[2], wA[3] };                                 \
    uint4 tB4 = { wB[0], wB[1], wB[2], wB[3] };                                 \
    u16x8 pfA = __builtin_bit_cast(u16x8, tA4);                                 \
    u16x8 pfB = __builtin_bit_cast(u16x8, tB4);                                 \
    __builtin_amdgcn_s_setprio(1);                                              \
    _Pragma("unroll")                                                           \
    for (int nt = 0; nt < 8; ++nt) {                                            \
      accOA[nt] = mfma_bf16(pfA, vfp[nt], accOA[nt]);                           \
      accOB[nt] = mfma_bf16(pfB, vfp[nt], accOB[nt]);                           \
    }                                                                           \
    __builtin_amdgcn_s_setprio(0);                                              \
  }

  // ---- prologue: stage tile 0; epoch 0 computes QK(0) and loads vfp(0) ----
  STAGE_LOAD(KT_OF(0));
  STAGE_WRITE(0);
  __syncthreads();
  {
    if (ntiles > 1) STAGE_LOAD(KT_OF(1));
    f32x4 nSA[2] = {}, nSB[2] = {};
    QK_PHASE(0);
    VF_LOAD(0);
    sSA[0] = nSA[0]; sSA[1] = nSA[1];
    sSB[0] = nSB[0]; sSB[1] = nSB[1];
    ktP = KT_OF(0);
    mskP = MSK_OF(0, ktP) ? 1 : 0;
    if (ntiles > 1) STAGE_WRITE(1);
    __syncthreads();
  }
  // ---- main loop: epoch i does QK(i) + finish(i-1) ----
  for (int i = 1; i < ntiles; ++i) {
    const int cur = i & 1;
    const bool more = (i + 1) < ntiles;
    if (more) STAGE_LOAD(KT_OF(i + 1));
    f32x4 nSA[2] = {}, nSB[2] = {};
    QK_PHASE(cur);
    FINISH();                    // softmax + PV of tile i-1 (registers only)
    VF_LOAD(cur);                // vfp <- V(i) (WAR on vfp orders this after PV)
    sSA[0] = nSA[0]; sSA[1] = nSA[1];
    sSB[0] = nSB[0]; sSB[1] = nSB[1];
    {
      const int ktc = KT_OF(i);
      ktP = ktc;
      mskP = MSK_OF(i, ktc) ? 1 : 0;
    }
    if (more) STAGE_WRITE(cur ^ 1);
    __syncthreads();
  }
  // ---- epilogue: finish last tile ----
  FINISH();
#undef STAGE_LOAD
#undef STAGE_WRITE
#undef QK_PHASE
#undef VF_LOAD
#undef SOFT
#undef FINISH
#undef KT_OF
#undef MSK_OF

  // final lsum reductions + normalize + store
  float lsA = (ls4A[0] + ls4A[1]) + (ls4A[2] + ls4A[3]);
  float lsB = (ls4B[0] + ls4B[1]) + (ls4B[2] + ls4B[3]);
  lsA += __shfl_xor(lsA, 16); lsA += __shfl_xor(lsA, 32);
  lsB += __shfl_xor(lsB, 16); lsB += __shfl_xor(lsB, 32);
  float lrA[4], lrB[4];
#pragma unroll
  for (int r = 0; r < 4; ++r) {
    lrA[r] = 1.0f / __shfl(lsA, hi * 4 + r);
    lrB[r] = 1.0f / __shfl(lsB, hi * 4 + r);
  }
#pragma unroll
  for (int nt = 0; nt < 8; ++nt)
#pragma unroll
    for (int r = 0; r < 4; ++r) {
      const int tA = qwA + hi * 4 + r;
      const int tB = qwB + hi * 4 + r;
      yb[(size_t)tA * 2048 + h * 128 + nt * 16 + lo] = f2bf(accOA[nt][r] * lrA[r]);
      yb[(size_t)tB * 2048 + h * 128 + nt * 16 + lo] = f2bf(accOB[nt][r] * lrB[r]);
    }
}

// ---------------- launch ----------------
extern "C" void kernel_launch(void* const* d_in, const int* in_sizes, int n_in,
                              void* d_out, int out_size, void* d_ws, size_t ws_size,
                              hipStream_t stream) {
  const float* x   = (const float*)d_in[0];
  const float* wq  = (const float*)d_in[1];
  const float* wk  = (const float*)d_in[2];
  const float* wv  = (const float*)d_in[3];
  const float* wo  = (const float*)d_in[4];
  const float* qkw = (const float*)d_in[5];
  (void)in_sizes; (void)n_in; (void)out_size; (void)ws_size;

  char* ws = (char*)d_ws;
  u16* xb    = (u16*)(ws);                          // 4096x2048   bf16 (16MiB)
  u16* wqkvb = (u16*)(ws + (16ull << 20));          // 3072x2048   bf16 (12MiB)
  u16* wob   = (u16*)(ws + (28ull << 20));          // 2048x2048   bf16 (8MiB)
  u16* qkvb  = (u16*)(ws + (36ull << 20));          // 4096x3072   bf16 (24MiB)
  u16* qb    = (u16*)(ws + (60ull << 20));          // 16x4096x128 bf16 (16MiB)
  u16* kb    = (u16*)(ws + (76ull << 20));          // 4x4096x128  bf16 (4MiB)
  u16* vtb   = (u16*)(ws + (80ull << 20));          // 4x128x4096  bf16 (4MiB)
  u16* yb    = (u16*)(ws + (84ull << 20));          // 4096x2048   bf16 (16MiB)

  k_cvt_all<<<18432, 256, 0, stream>>>(x, wq, wk, wv, wo, xb, wqkvb, wob);
  k_gemm_bt<true><<<dim3(24, 32), 256, 0, stream>>>(xb, wqkvb, qkvb, 4096, 3072, 2048);
  k_rope_tv<<<20992, 256, 0, stream>>>(qkvb, qkw, qb, kb, vtb);
  k_attn_mfma<<<512, 256, 0, stream>>>(qb, kb, vtb, yb);
  k_gemm_bt<false><<<dim3(16, 32), 256, 0, stream>>>(yb, wob, (float*)d_out, 4096, 2048, 2048);
}

// Round 21
// 308.522 us; speedup vs baseline: 1.2203x; 1.2203x over previous
//
#include <hip/hip_runtime.h>

typedef unsigned short u16;
typedef __bf16 bf16x8_t __attribute__((ext_vector_type(8)));
typedef float f32x4 __attribute__((ext_vector_type(4)));
typedef u16 u16x8 __attribute__((ext_vector_type(8)));
typedef u16 u16x4 __attribute__((ext_vector_type(4)));

__device__ __forceinline__ u16 f2bf(float f) {
  union { float f; unsigned u; } v; v.f = f;
  unsigned r = v.u + 0x7FFFu + ((v.u >> 16) & 1u);
  return (u16)(r >> 16);
}
__device__ __forceinline__ float bf2f(u16 b) {
  union { unsigned u; float f; } v; v.u = ((unsigned)b) << 16;
  return v.f;
}
__device__ __forceinline__ f32x4 mfma_bf16(u16x8 a, u16x8 b, f32x4 c) {
  return __builtin_amdgcn_mfma_f32_16x16x32_bf16(
      __builtin_bit_cast(bf16x8_t, a), __builtin_bit_cast(bf16x8_t, b), c, 0, 0, 0);
}
// two f32 -> two TRUNCATED bf16 in one v_perm_b32 (bytes: a.hi16 -> low, b.hi16 -> high)
__device__ __forceinline__ unsigned pack_bf16_trunc(float a, float b) {
  return __builtin_amdgcn_perm(__builtin_bit_cast(unsigned, b),
                               __builtin_bit_cast(unsigned, a), 0x07060302u);
}

// ---------------- fused f32 -> bf16 convert (x, wq, wk, wv, wo in one launch) --------
__global__ void k_cvt_all(const float* __restrict__ x,  const float* __restrict__ wq,
                          const float* __restrict__ wk, const float* __restrict__ wv,
                          const float* __restrict__ wo, u16* __restrict__ xb,
                          u16* __restrict__ wqkvb, u16* __restrict__ wob) {
  const int i = blockIdx.x * blockDim.x + threadIdx.x;   // float4 index, < 4718592
  const float* src;
  u16* dst;
  int off;
  if (i < 2097152)      { src = x;  dst = xb;               off = i; }
  else if (i < 3145728) { src = wq; dst = wqkvb;            off = i - 2097152; }
  else if (i < 3407872) { src = wk; dst = wqkvb + 4194304;  off = i - 3145728; }
  else if (i < 3670016) { src = wv; dst = wqkvb + 5242880;  off = i - 3407872; }
  else                  { src = wo; dst = wob;              off = i - 3670016; }
  float4 v = reinterpret_cast<const float4*>(src)[off];
  u16x4 o = { f2bf(v.x), f2bf(v.y), f2bf(v.z), f2bf(v.w) };
  reinterpret_cast<u16x4*>(dst)[off] = o;
}

// ---------------- GEMM: C[M][N] = A[M][K] * B[N][K]^T (both bf16 row-major, K-major) ----
template<bool BF16OUT>
__global__ __launch_bounds__(256, 2)
void k_gemm_bt(const u16* __restrict__ A, const u16* __restrict__ B,
               void* __restrict__ Cv, int M, int N, int K) {
  __shared__ u16 lA[128 * 64];
  __shared__ u16 lB[128 * 64];
  const int bm = blockIdx.y, bn = blockIdx.x;
  const int tid = threadIdx.x;
  const int wid = tid >> 6, lane = tid & 63;
  const int lo = lane & 15, hi = lane >> 4;
  const int wrow = (wid >> 1) * 64, wcol = (wid & 1) * 64;
  f32x4 acc[4][4] = {};
  const size_t abase = (size_t)(bm * 128) * K;
  const size_t bbase = (size_t)(bn * 128) * K;
  for (int kt = 0; kt < K; kt += 64) {
#pragma unroll
    for (int rr = 0; rr < 4; ++rr) {
      int e = (rr * 256 + tid) * 8;
      int row = e >> 6, col = e & 63;
      u16x8 va = *reinterpret_cast<const u16x8*>(A + abase + (size_t)row * K + kt + col);
      u16x8 vb = *reinterpret_cast<const u16x8*>(B + bbase + (size_t)row * K + kt + col);
      int sw = ((row * 64 + col) * 2) ^ ((row & 7) << 4);
      *reinterpret_cast<u16x8*>(reinterpret_cast<char*>(lA) + sw) = va;
      *reinterpret_cast<u16x8*>(reinterpret_cast<char*>(lB) + sw) = vb;
    }
    __syncthreads();
#pragma unroll
    for (int ks = 0; ks < 64; ks += 32) {
      u16x8 af[4], bfr[4];
#pragma unroll
      for (int mi = 0; mi < 4; ++mi) {
        int row = wrow + mi * 16 + lo, col = ks + hi * 8;
        int sw = ((row * 64 + col) * 2) ^ ((row & 7) << 4);
        af[mi] = *reinterpret_cast<const u16x8*>(reinterpret_cast<char*>(lA) + sw);
      }
#pragma unroll
      for (int ni = 0; ni < 4; ++ni) {
        int row = wcol + ni * 16 + lo, col = ks + hi * 8;
        int sw = ((row * 64 + col) * 2) ^ ((row & 7) << 4);
        bfr[ni] = *reinterpret_cast<const u16x8*>(reinterpret_cast<char*>(lB) + sw);
      }
#pragma unroll
      for (int mi = 0; mi < 4; ++mi)
#pragma unroll
        for (int ni = 0; ni < 4; ++ni)
          acc[mi][ni] = mfma_bf16(af[mi], bfr[ni], acc[mi][ni]);
    }
    __syncthreads();
  }
#pragma unroll
  for (int mi = 0; mi < 4; ++mi)
#pragma unroll
    for (int ni = 0; ni < 4; ++ni)
#pragma unroll
      for (int r = 0; r < 4; ++r) {
        int row = bm * 128 + wrow + mi * 16 + hi * 4 + r;
        int col = bn * 128 + wcol + ni * 16 + lo;
        if (BF16OUT)
          ((u16*)Cv)[(size_t)row * N + col] = f2bf(acc[mi][ni][r]);
        else
          ((float*)Cv)[(size_t)row * N + col] = acc[mi][ni][r];
      }
}

// ---------------- FUSED RoPE + QK RMSNorm + V transpose (one dispatch) ----------------
// blocks [0, 20480): rope+norm on (t, head) pairs; Q pre-scaled by scale*log2e.
// blocks [20480, 20992): V transpose -> V^T [4][128][4096] in MFMA slot order.
#define ATT_SL2E 0.12754276432973518f   /* (1/sqrt(128)) * log2(e) */
__global__ void k_rope_tv(const u16* __restrict__ QKV, const float* __restrict__ qkw,
                          u16* __restrict__ qb, u16* __restrict__ kb,
                          u16* __restrict__ vtb) {
  __shared__ float lt[64][65];
  const int tid = threadIdx.x;
  if (blockIdx.x < 20480) {
    int gw = blockIdx.x * 4 + (tid >> 6);
    int lane = tid & 63;
    int t = gw / 20, hh = gw - t * 20;
    const u16* src = QKV + (size_t)t * 3072 + (hh < 16 ? hh * 128 : 2048 + (hh - 16) * 128);
    float x1 = bf2f(src[lane]), x2 = bf2f(src[lane + 64]);
    float invf = exp2f(-(float)lane * (13.287712379549449f / 64.0f)); // 10000^(-lane/64)
    float fr = (float)t * invf;
    float sn, cs;
    sincosf(fr, &sn, &cs);
    float o1 = x1 * cs - x2 * sn, o2 = x1 * sn + x2 * cs;
    float ss = o1 * o1 + o2 * o2;
#pragma unroll
    for (int off = 32; off > 0; off >>= 1) ss += __shfl_xor(ss, off);
    float inv = rsqrtf(ss * (1.0f / 128.0f) + 1e-6f);
    inv *= (hh < 16) ? ATT_SL2E : 1.0f;   // fold attention scale+log2e into Q
    o1 *= inv * qkw[lane];
    o2 *= inv * qkw[lane + 64];
    u16* dst = (hh < 16) ? (qb + ((size_t)hh * 4096 + t) * 128)
                         : (kb + ((size_t)(hh - 16) * 4096 + t) * 128);
    dst[lane] = f2bf(o1);
    dst[lane + 64] = f2bf(o2);
  } else {
    int b = blockIdx.x - 20480;
    int dt = b & 1, tt = (b >> 1) & 63, kv = b >> 7;
#pragma unroll
    for (int rr = 0; rr < 16; ++rr) {
      int row = rr * 4 + (tid >> 6);
      int col = tid & 63;
      lt[row][col] = bf2f(QKV[(size_t)(tt * 64 + row) * 3072 + 2560 + kv * 128 + dt * 64 + col]);
    }
    __syncthreads();
#pragma unroll
    for (int pp = 0; pp < 2; ++pp) {
      int idx = pp * 256 + tid;
      int dr = idx >> 3, tc = (idx & 7) * 8;
      const int grp = tc >> 5;           // 32-key group within the 64-key tile
      const int pb = tc & 31;            // position base within group (8-aligned)
      u16x8 o;
#pragma unroll
      for (int i = 0; i < 8; ++i) {
        const int p = pb + i;
        const int g = (p & 3) | (((p >> 3) & 3) << 2) | (((p >> 2) & 1) << 4);
        o[i] = f2bf(lt[grp * 32 + g][dr]);
      }
      *reinterpret_cast<u16x8*>(vtb + (size_t)(kv * 128 + dt * 64 + dr) * 4096 + tt * 64 + tc) = o;
    }
  }
}

// ---------------- MFMA flash attention, 2-deep pipeline (T15: QK[i] || finish[i-1]) --
// attend: j in [4, q-1023) union [q+1, 4096); K+V LDS-staged; XCD-kvh swizzle; setprio.
// SCALAR lsum (R19 verbatim): VGPR must stay <= 128 (HW quantum; waves halve above it).
#define KPAD 136   /* 32 x 136 u16: 272B = 17*16B */
#define VPAD 40    /* 128 x 40 u16: 80B = 5*16B  */

__global__ __launch_bounds__(256)
void k_attn_mfma(const u16* __restrict__ qb, const u16* __restrict__ kb,
                 const u16* __restrict__ vtb, u16* __restrict__ yb) {
  __shared__ u16 sK[2][32][KPAD];
  __shared__ u16 sV[2][128][VPAD];   // slot-order keys
  // XCD-kvh swizzle (bijective on [0,512)): xcd = id&7 owns work [xcd*64, xcd*64+64)
  const int id = blockIdx.x;
  const int work = (id & 7) * 64 + (id >> 3);
  const int kvh = work >> 7;               // 2 XCDs per kvh
  const int rem = work & 127;
  const int h = kvh * 4 + (rem >> 5);
  const int qt = rem & 31;
  const int tid = threadIdx.x;
  const int wid = tid >> 6, lane = tid & 63;
  const int lo = lane & 15, hi = lane >> 4;
  const int q0 = qt * 128;
  const int qwA = q0 + wid * 16;          // fragment A queries
  const int qwB = qwA + 64;               // fragment B queries
  const int qrowA = qwA + lo, qrowB = qwB + lo;
  const u16* qpA = qb + ((size_t)h * 4096 + qrowA) * 128;
  const u16* qpB = qb + ((size_t)h * 4096 + qrowB) * 128;
  u16x8 qfA[4], qfB[4];
#pragma unroll
  for (int dc = 0; dc < 4; ++dc) {
    qfA[dc] = *reinterpret_cast<const u16x8*>(qpA + dc * 32 + hi * 8);
    qfB[dc] = *reinterpret_cast<const u16x8*>(qpB + dc * 32 + hi * 8);
  }
  f32x4 accOA[8] = {}, accOB[8] = {};
  float lsA = 0.0f, lsB = 0.0f;
  const u16* kbase = kb + (size_t)kvh * 4096 * 128;
  const u16* vb = vtb + (size_t)kvh * 128 * 4096;

  // block-uniform tile list over 128 queries
  int past_tiles = 0;
  const int pe = q0 + 127 - 1024;
  if (pe >= 4) past_tiles = (pe >> 5) + 1;
  const int fstart = (q0 + 1) >> 5;
  const int ntiles = past_tiles + (128 - fstart);
  // mask-free (uniform over all 128 queries): past kt in [1, (q0-1055)>>5]; future kt >= (q0>>5)+4
  const int safe_past_hi = (q0 >= 1056) ? ((q0 - 1055) >> 5) : 0;
  const int funmask = (q0 >> 5) + 4;

#define KT_OF(i) (((i) < past_tiles) ? (i) : (fstart + ((i) - past_tiles)))
#define MSK_OF(i, ktv) (((i) < past_tiles) ? (((ktv) == 0) || ((ktv) > safe_past_hi)) \
                                           : ((ktv) < funmask))

  // pipeline registers: S and V of the previous (unfinished) tile
  f32x4 sSA[2], sSB[2];
  u16x8 vfp[8];
  int ktP = 0, mskP = 0;

  u16x8 kr[2], vr[2];
#define STAGE_LOAD(KT)                                                          \
  {                                                                             \
    const int kt_ = (KT);                                                       \
    _Pragma("unroll")                                                           \
    for (int p = 0; p < 2; ++p) {                                               \
      const int c = tid + p * 256;                                              \
      kr[p] = *reinterpret_cast<const u16x8*>(                                  \
          kbase + (size_t)(kt_ * 32 + (c >> 4)) * 128 + (c & 15) * 8);          \
      vr[p] = *reinterpret_cast<const u16x8*>(                                  \
          vb + (size_t)(c >> 2) * 4096 + kt_ * 32 + (c & 3) * 8);               \
    }                                                                           \
  }
#define STAGE_WRITE(BUF)                                                        \
  {                                                                             \
    const int b_ = (BUF);                                                       \
    _Pragma("unroll")                                                           \
    for (int p = 0; p < 2; ++p) {                                               \
      const int c = tid + p * 256;                                              \
      *reinterpret_cast<u16x8*>(&sK[b_][c >> 4][(c & 15) * 8]) = kr[p];         \
      *reinterpret_cast<u16x8*>(&sV[b_][c >> 2][(c & 3) * 8]) = vr[p];          \
    }                                                                           \
  }
#define QK_PHASE(CUR)                                                           \
    __builtin_amdgcn_s_setprio(1);                                              \
    _Pragma("unroll")                                                           \
    for (int sub = 0; sub < 2; ++sub)                                           \
      _Pragma("unroll")                                                         \
      for (int dc = 0; dc < 4; ++dc) {                                          \
        u16x8 kf = *reinterpret_cast<const u16x8*>(                             \
            &sK[CUR][sub * 16 + lo][dc * 32 + hi * 8]);                         \
        nSA[sub] = mfma_bf16(kf, qfA[dc], nSA[sub]);                            \
        nSB[sub] = mfma_bf16(kf, qfB[dc], nSB[sub]);                            \
      }                                                                         \
    __builtin_amdgcn_s_setprio(0);
#define VF_LOAD(CUR)                                                            \
    _Pragma("unroll")                                                           \
    for (int nt = 0; nt < 8; ++nt)                                              \
      vfp[nt] = *reinterpret_cast<const u16x8*>(&sV[CUR][nt * 16 + lo][hi * 8]);
  // softmax of the DEFERRED tile (registers sS*, ktP); MSKLIT folds at compile time
#define SOFT(MSKLIT)                                                            \
    _Pragma("unroll")                                                           \
    for (int sub = 0; sub < 2; ++sub) {                                         \
      float eA[4], eB[4];                                                       \
      _Pragma("unroll")                                                         \
      for (int r = 0; r < 4; ++r) {                                             \
        float pA = exp2f(sSA[sub][r]);                                          \
        float pB = exp2f(sSB[sub][r]);                                          \
        if (MSKLIT) {                                                           \
          const int j = ktP * 32 + sub * 16 + hi * 4 + r;                       \
          const bool okA = (j > qrowA) || (((qrowA - j) >= 1024) && (j >= 4));  \
          const bool okB = (j > qrowB) || (((qrowB - j) >= 1024) && (j >= 4));  \
          pA = okA ? pA : 0.0f;                                                 \
          pB = okB ? pB : 0.0f;                                                 \
        }                                                                       \
        lsA += pA; lsB += pB;                                                   \
        eA[r] = pA; eB[r] = pB;                                                 \
      }                                                                         \
      wA[sub * 2]     = pack_bf16_trunc(eA[0], eA[1]);                          \
      wA[sub * 2 + 1] = pack_bf16_trunc(eA[2], eA[3]);                          \
      wB[sub * 2]     = pack_bf16_trunc(eB[0], eB[1]);                          \
      wB[sub * 2 + 1] = pack_bf16_trunc(eB[2], eB[3]);                          \
    }
#define FINISH()                                                                \
  {                                                                             \
    unsigned wA[4], wB[4];                                                      \
    if (mskP) { SOFT(true) } else { SOFT(false) }                               \
    uint4 tA4 = { wA[0], wA[1], wA[2], wA[3] };                                 \
    uint4 tB4 = { wB[0], wB[1], wB[2], wB[3] };                                 \
    u16x8 pfA = __builtin_bit_cast(u16x8, tA4);                                 \
    u16x8 pfB = __builtin_bit_cast(u16x8, tB4);                                 \
    __builtin_amdgcn_s_setprio(1);                                              \
    _Pragma("unroll")                                                           \
    for (int nt = 0; nt < 8; ++nt) {                                            \
      accOA[nt] = mfma_bf16(pfA, vfp[nt], accOA[nt]);                           \
      accOB[nt] = mfma_bf16(pfB, vfp[nt], accOB[nt]);                           \
    }                                                                           \
    __builtin_amdgcn_s_setprio(0);                                              \
  }

  // ---- prologue: stage tile 0; epoch 0 computes QK(0) and loads vfp(0) ----
  STAGE_LOAD(KT_OF(0));
  STAGE_WRITE(0);
  __syncthreads();
  {
    if (ntiles > 1) STAGE_LOAD(KT_OF(1));
    f32x4 nSA[2] = {}, nSB[2] = {};
    QK_PHASE(0);
    VF_LOAD(0);
    sSA[0] = nSA[0]; sSA[1] = nSA[1];
    sSB[0] = nSB[0]; sSB[1] = nSB[1];
    ktP = KT_OF(0);
    mskP = MSK_OF(0, ktP) ? 1 : 0;
    if (ntiles > 1) STAGE_WRITE(1);
    __syncthreads();
  }
  // ---- main loop: epoch i does QK(i) + finish(i-1) ----
  for (int i = 1; i < ntiles; ++i) {
    const int cur = i & 1;
    const bool more = (i + 1) < ntiles;
    if (more) STAGE_LOAD(KT_OF(i + 1));
    f32x4 nSA[2] = {}, nSB[2] = {};
    QK_PHASE(cur);
    FINISH();                    // softmax + PV of tile i-1 (registers only)
    VF_LOAD(cur);                // vfp <- V(i) (WAR on vfp orders this after PV)
    sSA[0] = nSA[0]; sSA[1] = nSA[1];
    sSB[0] = nSB[0]; sSB[1] = nSB[1];
    {
      const int ktc = KT_OF(i);
      ktP = ktc;
      mskP = MSK_OF(i, ktc) ? 1 : 0;
    }
    if (more) STAGE_WRITE(cur ^ 1);
    __syncthreads();
  }
  // ---- epilogue: finish last tile ----
  FINISH();
#undef STAGE_LOAD
#undef STAGE_WRITE
#undef QK_PHASE
#undef VF_LOAD
#undef SOFT
#undef FINISH
#undef KT_OF
#undef MSK_OF

  // final lsum reductions + normalize + store
  lsA += __shfl_xor(lsA, 16); lsA += __shfl_xor(lsA, 32);
  lsB += __shfl_xor(lsB, 16); lsB += __shfl_xor(lsB, 32);
  float lrA[4], lrB[4];
#pragma unroll
  for (int r = 0; r < 4; ++r) {
    lrA[r] = 1.0f / __shfl(lsA, hi * 4 + r);
    lrB[r] = 1.0f / __shfl(lsB, hi * 4 + r);
  }
#pragma unroll
  for (int nt = 0; nt < 8; ++nt)
#pragma unroll
    for (int r = 0; r < 4; ++r) {
      const int tA = qwA + hi * 4 + r;
      const int tB = qwB + hi * 4 + r;
      yb[(size_t)tA * 2048 + h * 128 + nt * 16 + lo] = f2bf(accOA[nt][r] * lrA[r]);
      yb[(size_t)tB * 2048 + h * 128 + nt * 16 + lo] = f2bf(accOB[nt][r] * lrB[r]);
    }
}

// ---------------- launch ----------------
extern "C" void kernel_launch(void* const* d_in, const int* in_sizes, int n_in,
                              void* d_out, int out_size, void* d_ws, size_t ws_size,
                              hipStream_t stream) {
  const float* x   = (const float*)d_in[0];
  const float* wq  = (const float*)d_in[1];
  const float* wk  = (const float*)d_in[2];
  const float* wv  = (const float*)d_in[3];
  const float* wo  = (const float*)d_in[4];
  const float* qkw = (const float*)d_in[5];
  (void)in_sizes; (void)n_in; (void)out_size; (void)ws_size;

  char* ws = (char*)d_ws;
  u16* xb    = (u16*)(ws);                          // 4096x2048   bf16 (16MiB)
  u16* wqkvb = (u16*)(ws + (16ull << 20));          // 3072x2048   bf16 (12MiB)
  u16* wob   = (u16*)(ws + (28ull << 20));          // 2048x2048   bf16 (8MiB)
  u16* qkvb  = (u16*)(ws + (36ull << 20));          // 4096x3072   bf16 (24MiB)
  u16* qb    = (u16*)(ws + (60ull << 20));          // 16x4096x128 bf16 (16MiB)
  u16* kb    = (u16*)(ws + (76ull << 20));          // 4x4096x128  bf16 (4MiB)
  u16* vtb   = (u16*)(ws + (80ull << 20));          // 4x128x4096  bf16 (4MiB)
  u16* yb    = (u16*)(ws + (84ull << 20));          // 4096x2048   bf16 (16MiB)

  k_cvt_all<<<18432, 256, 0, stream>>>(x, wq, wk, wv, wo, xb, wqkvb, wob);
  k_gemm_bt<true><<<dim3(24, 32), 256, 0, stream>>>(xb, wqkvb, qkvb, 4096, 3072, 2048);
  k_rope_tv<<<20992, 256, 0, stream>>>(qkvb, qkw, qb, kb, vtb);
  k_attn_mfma<<<512, 256, 0, stream>>>(qb, kb, vtb, yb);
  k_gemm_bt<false><<<dim3(16, 32), 256, 0, stream>>>(yb, wob, (float*)d_out, 4096, 2048, 2048);
}